// Round 3
// baseline (445.862 us; speedup 1.0000x reference)
//
#include <hip/hip_runtime.h>
#include <hip/hip_bf16.h>

// Problem dims (fixed by the reference):
//   x: (256*14*14, 384) fp32  -> M = 50176, K = 384
//   W: (1536, 384) fp32       -> N = 1536 (row-major N x K, i.e. B^T layout)
//   out: (M, N) fp32
#define M_ROWS 50176
#define K_DIM  384
#define N_DIM  1536

typedef __bf16 bf16;
typedef bf16  bf16x8 __attribute__((ext_vector_type(8)));
typedef float f32x4  __attribute__((ext_vector_type(4)));

typedef __attribute__((address_space(1))) const void* addr1_cptr;
typedef __attribute__((address_space(3))) void*       addr3_ptr;

// Async global->LDS, 16B per lane. LDS dest = wave-uniform base + lane*16.
__device__ __forceinline__ void async_copy16(const void* g, void* l) {
    __builtin_amdgcn_global_load_lds((addr1_cptr)g, (addr3_ptr)l, 16, 0, 0);
}

// Fast exact GELU: 0.5*y*(1+erf(y/sqrt(2))) with A&S 7.1.26 erf
// (max |err| 1.5e-7 on erf -> negligible vs bf16 matmul noise).
__device__ __forceinline__ float gelu_exact(float y) {
    const float ax = fabsf(y) * 0.70710678118654752f;   // |y|/sqrt(2)
    const float t  = __builtin_amdgcn_rcpf(1.0f + 0.3275911f * ax);
    const float p  = t * (0.254829592f +
                     t * (-0.284496736f +
                     t * (1.421413741f +
                     t * (-1.453152027f +
                     t * 1.061405429f))));
    const float e  = __expf(-ax * ax);
    const float er = copysignf(1.0f - p * e, y);        // erf(y/sqrt(2))
    const float h  = 0.5f * y;
    return h + h * er;                                  // 0.5y(1+erf)
}

// ---------------------------------------------------------------------------
// Kernel 1: fused LayerNorm (fp32 -> bf16) + W fp32->bf16 conversion tail.
// LN: half-wave per row (2 rows/wave, 8 rows/block), float4 loads (16B/lane,
// G13 coalescing sweet spot). Blocks >= LN_BLOCKS do the W conversion.
// ---------------------------------------------------------------------------
#define LN_BLOCKS   (M_ROWS / 8)                   // 6272
#define WCVT_BLOCKS ((N_DIM * K_DIM / 2) / 256)    // 1152

__global__ __launch_bounds__(256) void ln_wcvt_kernel(
    const float* __restrict__ x, const float* __restrict__ gamma,
    const float* __restrict__ beta, bf16* __restrict__ xn,
    const float* __restrict__ W, bf16* __restrict__ Wb) {
    const int t = threadIdx.x;

    if (blockIdx.x >= LN_BLOCKS) {
        // ---- W fp32 -> bf16 tail ----
        const int i = (blockIdx.x - LN_BLOCKS) * 256 + t;  // over float2
        float2 v = ((const float2*)W)[i];
        __hip_bfloat162 h;
        h.x = __float2bfloat16(v.x);
        h.y = __float2bfloat16(v.y);
        ((__hip_bfloat162*)Wb)[i] = h;
        return;
    }

    // ---- LayerNorm: wave handles 2 rows, half-wave (32 lanes) per row ----
    const int wave = t >> 6, lane = t & 63;
    const int l32  = lane & 31;
    const long row = (long)blockIdx.x * 8 + wave * 2 + (lane >> 5);

    const float4* xr = (const float4*)(x + row * K_DIM);  // 96 float4 per row
    float4 v[3];
    v[0] = xr[l32];
    v[1] = xr[l32 + 32];
    v[2] = xr[l32 + 64];

    float s = 0.f, q = 0.f;
#pragma unroll
    for (int i = 0; i < 3; ++i) {
        s += v[i].x + v[i].y + v[i].z + v[i].w;
        q += v[i].x * v[i].x + v[i].y * v[i].y +
             v[i].z * v[i].z + v[i].w * v[i].w;
    }
    // Reduce across the 32 lanes of this half-wave (xor offsets < 32 keep
    // lane>>5 membership).
#pragma unroll
    for (int off = 16; off > 0; off >>= 1) {
        s += __shfl_xor(s, off);
        q += __shfl_xor(q, off);
    }
    const float mean = s * (1.0f / K_DIM);
    const float var  = q * (1.0f / K_DIM) - mean * mean;
    const float rstd = rsqrtf(var + 1e-6f);

    const float4* g4 = (const float4*)gamma;
    const float4* b4 = (const float4*)beta;
    bf16* orow = xn + row * K_DIM;
#pragma unroll
    for (int i = 0; i < 3; ++i) {
        const float4 g  = g4[l32 + i * 32];
        const float4 bb = b4[l32 + i * 32];
        __hip_bfloat162 h0, h1;
        h0.x = __float2bfloat16((v[i].x - mean) * rstd * g.x + bb.x);
        h0.y = __float2bfloat16((v[i].y - mean) * rstd * g.y + bb.y);
        h1.x = __float2bfloat16((v[i].z - mean) * rstd * g.z + bb.z);
        h1.y = __float2bfloat16((v[i].w - mean) * rstd * g.w + bb.w);
        __hip_bfloat162* o2 = (__hip_bfloat162*)(orow + (l32 + i * 32) * 4);
        o2[0] = h0;
        o2[1] = h1;
    }
}

// ---------------------------------------------------------------------------
// Kernel 2: GEMM C = A(M x K, bf16) @ W^T (W is N x K, bf16) + bias, GELU.
//
// 128x128 block tile (m103: best tile for the simple-loop structure), BK=32,
// 4 waves (2x2), each wave a 64x64 quadrant as 4x4 grid of 16x16x32 MFMA
// tiles (verified fragment layout/swizzle).
//
// Ring-3 LDS (48 KB) -> 3 blocks/CU: one block's epilogue (GELU + stores)
// overlaps TWO other blocks' K-loops, barriers sync only 4 waves.
// Distance-2 prefetch; STAGE = 4 global_load_lds -> counted boundary wait
// s_waitcnt vmcnt(4) (never 0 in steady state). No sched_barrier (m141).
// Plain stores (no nt): m201 template + 6.4 TB/s fills both use plain
// stores; nt may defeat L2 write-combining of 64 B quad segments.
//
// XCD swizzle (T1): nwg = 4704 = 8*588, simple bijective chunked form;
// x-fast within a chunk so the 12 blocks sharing an A-panel run
// consecutively on one XCD (panel lives in one L2, reused 12x).
// ---------------------------------------------------------------------------
#define BM 128
#define BN 128
#define BK 32
#define NKT (K_DIM / BK)               // 12
#define GRID_X (N_DIM / BN)            // 12
#define GRID_Y (M_ROWS / BM)           // 392
#define NWG    (GRID_X * GRID_Y)       // 4704
#define WG_PER_XCD (NWG / 8)           // 588

__global__ __launch_bounds__(256, 3) void gemm_kernel(
    const bf16* __restrict__ A,    // [M][K]
    const bf16* __restrict__ B,    // [N][K]  (= W in bf16)
    const float* __restrict__ bias,
    float* __restrict__ out) {
    __shared__ __align__(16) bf16 Al[3][BM * BK];  // 3 x 8 KB
    __shared__ __align__(16) bf16 Bl[3][BN * BK];  // 3 x 8 KB

    const int t = threadIdx.x;
    const int wave = t >> 6, lane = t & 63;
    const int wr = wave >> 1, wc = wave & 1;     // 2x2 wave grid
    const int lr = lane & 15, quad = lane >> 4;  // MFMA lane decomposition

    // XCD-chunked bijective swizzle.
    const int lin = blockIdx.y * GRID_X + blockIdx.x;
    const int swz = (lin & 7) * WG_PER_XCD + (lin >> 3);
    const int bx  = swz % GRID_X;
    const int by  = swz / GRID_X;
    const long m0 = (long)by * BM;
    const int  n0 = bx * BN;

    // Staging: tile = 128 rows x 32 K bf16 = 8 KB = 512 x 16B chunks.
    // Chunk e: row = e>>2, slot_chunk = e&3 holds global chunk
    // gc = (e&3) ^ ((row>>1)&3) (pre-swizzled global src, linear LDS).
    // 256 threads -> 2 chunks each per tile (e = t and 256+t).
    const int e1 = 256 + t;
    const int r0 = t >> 2,  r1 = e1 >> 2;
    const int c0 = (t & 3)  ^ ((r0 >> 1) & 3);
    const int c1 = (e1 & 3) ^ ((r1 >> 1) & 3);
    const bf16* gA0 = A + (m0 + r0) * K_DIM + c0 * 8;
    const bf16* gA1 = A + (m0 + r1) * K_DIM + c1 * 8;
    const bf16* gB0 = B + (long)(n0 + r0) * K_DIM + c0 * 8;
    const bf16* gB1 = B + (long)(n0 + r1) * K_DIM + c1 * 8;

    const int ldsOff0 = (wave * 64) * 16;          // wave-uniform dest (bytes)
    const int ldsOff1 = (256 + wave * 64) * 16;

#define STAGE(slot, kb)                                                   \
    do {                                                                  \
        async_copy16(gA0 + (kb) * BK, (char*)Al[slot] + ldsOff0);         \
        async_copy16(gA1 + (kb) * BK, (char*)Al[slot] + ldsOff1);         \
        async_copy16(gB0 + (kb) * BK, (char*)Bl[slot] + ldsOff0);         \
        async_copy16(gB1 + (kb) * BK, (char*)Bl[slot] + ldsOff1);         \
    } while (0)

    f32x4 acc[4][4];
#pragma unroll
    for (int i = 0; i < 4; ++i)
#pragma unroll
        for (int j = 0; j < 4; ++j)
            acc[i][j] = (f32x4){0.f, 0.f, 0.f, 0.f};

    // LDS read offsets: row r reads chunk quad swizzled by ((r>>1)&3);
    // 16-row fragment bases are multiples of 16 so only lr enters the XOR.
    const int sw   = (quad ^ ((lr >> 1) & 3)) * 8;
    const int aoff = (wr * 64 + lr) * BK + sw;
    const int boff = (wc * 64 + lr) * BK + sw;

    // Prologue: tiles 0,1 in flight (8 loads); wait tile 0 -> vmcnt(4).
    STAGE(0, 0);
    STAGE(1, 1);
    asm volatile("s_waitcnt vmcnt(4)" ::: "memory");
    __builtin_amdgcn_s_barrier();

#pragma unroll
    for (int kb = 0; kb < NKT; ++kb) {
        if (kb + 2 < NKT) STAGE((kb + 2) % 3, kb + 2);

        const bf16* Ab = Al[kb % 3] + aoff;
        const bf16* Bb = Bl[kb % 3] + boff;
        bf16x8 a[4], b[4];
#pragma unroll
        for (int i = 0; i < 4; ++i) a[i] = *(const bf16x8*)(Ab + i * 16 * BK);
#pragma unroll
        for (int j = 0; j < 4; ++j) b[j] = *(const bf16x8*)(Bb + j * 16 * BK);

        __builtin_amdgcn_s_setprio(1);
#pragma unroll
        for (int i = 0; i < 4; ++i)
#pragma unroll
            for (int j = 0; j < 4; ++j)
                acc[i][j] = __builtin_amdgcn_mfma_f32_16x16x32_bf16(
                    a[i], b[j], acc[i][j], 0, 0, 0);
        __builtin_amdgcn_s_setprio(0);

        // Boundary: tile kb+1 landed; keep kb+2's 4 loads in flight.
        if (kb + 2 < NKT) {
            asm volatile("s_waitcnt vmcnt(4)" ::: "memory");
        } else if (kb + 1 < NKT) {
            asm volatile("s_waitcnt vmcnt(0)" ::: "memory");
        }
        if (kb + 1 < NKT) __builtin_amdgcn_s_barrier();
    }
#undef STAGE

    // Epilogue: C/D layout col = lane&15, row = quad*4 + reg [m89/m91].
    float bb[4];
#pragma unroll
    for (int j = 0; j < 4; ++j) bb[j] = bias[n0 + wc * 64 + j * 16 + lr];

#pragma unroll
    for (int i = 0; i < 4; ++i) {
        const long grow0 = m0 + wr * 64 + i * 16 + quad * 4;
#pragma unroll
        for (int j = 0; j < 4; ++j) {
            const int gcol = n0 + wc * 64 + j * 16 + lr;
#pragma unroll
            for (int r = 0; r < 4; ++r) {
                const float y = acc[i][j][r] + bb[j];
                out[(grow0 + r) * (long)N_DIM + gcol] = gelu_exact(y);
            }
        }
    }
}

extern "C" void kernel_launch(void* const* d_in, const int* in_sizes, int n_in,
                              void* d_out, int out_size, void* d_ws, size_t ws_size,
                              hipStream_t stream) {
    (void)in_sizes; (void)n_in; (void)out_size; (void)ws_size;
    const float* x     = (const float*)d_in[0];
    const float* gamma = (const float*)d_in[1];
    const float* beta  = (const float*)d_in[2];
    const float* W     = (const float*)d_in[3];
    const float* b     = (const float*)d_in[4];
    float* out = (float*)d_out;

    // Workspace layout: xn bf16 [M][K] then Wb bf16 [N][K] (~39.7 MB total).
    bf16* xn = (bf16*)d_ws;
    bf16* Wb = (bf16*)((char*)d_ws + (size_t)M_ROWS * K_DIM * sizeof(bf16));

    ln_wcvt_kernel<<<LN_BLOCKS + WCVT_BLOCKS, 256, 0, stream>>>(
        x, gamma, beta, xn, W, Wb);

    dim3 grid(GRID_X, GRID_Y);
    gemm_kernel<<<grid, 256, 0, stream>>>(xn, Wb, b, out);
}